// Round 10
// baseline (305.836 us; speedup 1.0000x reference)
//
#include <hip/hip_runtime.h>
#include <hip/hip_bf16.h>

typedef unsigned short u16;
typedef unsigned int   u32;
typedef __bf16 bf16x8 __attribute__((ext_vector_type(8)));
typedef float  f32x4  __attribute__((ext_vector_type(4)));
typedef u16    u16x8  __attribute__((ext_vector_type(8)));
typedef u16    u16x4  __attribute__((ext_vector_type(4)));

#define MFMA16(a,b,c) __builtin_amdgcn_mfma_f32_16x16x32_bf16(a,b,c,0,0,0)
#define LOG2E 1.4426950408889634f

__device__ __forceinline__ u16 f2b(float f) {
    u32 u = __builtin_bit_cast(u32, f);
    u32 r = (u + 0x7FFFu + ((u >> 16) & 1u)) >> 16;  // RNE
    return (u16)r;
}

typedef const __attribute__((address_space(1))) u32* gaddr_t;
typedef __attribute__((address_space(3))) u32*       laddr_t;
__device__ __forceinline__ void gl_lds16(const void* g, void* l) {
    __builtin_amdgcn_global_load_lds((gaddr_t)g, (laddr_t)l, 16, 0, 0);
}

// ---------------- fused prep: cast H (blocks 0..4095) | transpose W (4096..5119) | bias (5120..5375) ----------------
__global__ __launch_bounds__(256) void prep_kernel(
        const float* __restrict__ H, const float* __restrict__ wq,
        const float* __restrict__ wk, const float* __restrict__ wv,
        const float* __restrict__ wo, const float* __restrict__ rel_bias,
        u16* __restrict__ Hb, u16* __restrict__ Wt, u16* __restrict__ Wot,
        float* __restrict__ tab) {
    __shared__ u16 tile[64 * 72];
    int bi = blockIdx.x;
    int t = threadIdx.x;
    if (bi < 4096) {
        // cast hidden_states fp32 -> bf16
        int i = (bi * 256 + t) * 8;
        float4 a = *(const float4*)(H + i);
        float4 b = *(const float4*)(H + i + 4);
        u16x8 o = { f2b(a.x), f2b(a.y), f2b(a.z), f2b(a.w),
                    f2b(b.x), f2b(b.y), f2b(b.z), f2b(b.w) };
        *(u16x8*)(Hb + i) = o;
    } else if (bi < 5120) {
        // transpose+cast weights [K=1024][N=1024] -> bf16 [N][K]
        int g2 = bi - 4096;
        int g = g2 >> 8, rem = g2 & 255;
        int n0 = (rem >> 4) * 64, k0 = (rem & 15) * 64;
        const float* src = (g == 0) ? wq : (g == 1) ? wk : (g == 2) ? wv : wo;
        u16* dst = (g < 3) ? (Wt + g * 1048576) : Wot;
#pragma unroll
        for (int rr = 0; rr < 4; ++rr) {
            int idx = rr * 256 + t;
            int kr = idx >> 4, c = idx & 15;
            float4 v = *(const float4*)(src + (k0 + kr) * 1024 + n0 + c * 4);
            u16x4 o = { f2b(v.x), f2b(v.y), f2b(v.z), f2b(v.w) };
            *(u16x4*)&tile[kr * 72 + c * 4] = o;
        }
        __syncthreads();
#pragma unroll
        for (int rr = 0; rr < 2; ++rr) {
            int idx = rr * 256 + t;
            int n = idx >> 3, c = idx & 7;
            u16x8 o;
#pragma unroll
            for (int j = 0; j < 8; ++j) o[j] = tile[(c * 8 + j) * 72 + n];
            *(u16x8*)(dst + (n0 + n) * 1024 + k0 + c * 8) = o;
        }
    } else {
        // bias_tab[h][delta+2048] = rel_bias[bucket(delta)][h] * log2e
        int i = (bi - 5120) * 256 + t;    // 16*4096
        int h = i >> 12;
        int idx = i & 4095;
        int delta = idx - 2048;            // k - q
        int bucket = (delta > 0) ? 16 : 0;
        int rp = delta < 0 ? -delta : delta;
        if (rp < 8) {
            bucket += rp;
        } else {
            double v = log((double)rp / 8.0) / log(16.0) * 8.0;
            int tt = (int)v;
            int b2 = 8 + tt;
            bucket += (b2 < 15) ? b2 : 15;
        }
        tab[h * 4096 + idx] = rel_bias[bucket * 16 + h] * LOG2E;
    }
}

// ---------------- GEMM: C[M,N] = A[M,K] * Bt[N,K]^T, bf16 MFMA ----------------
// MODE 0: N=3072 qkv. q,k columns -> Qb (scaled log2e) / Kb as [bh][s][64].
//         v columns (n0>=2048) -> transposed in LDS, stored Vt [bh][d][s].
// MODE 1: fp32 output row-major [M][N].
template <int MODE>
__global__ __launch_bounds__(256) void gemm_bt(
        const u16* __restrict__ A, const u16* __restrict__ Bt, int K, int N,
        u16* __restrict__ q_out, u16* __restrict__ k_out, u16* __restrict__ v_out,
        float* __restrict__ f_out) {
    __shared__ u16 As[128 * 32];
    __shared__ u16 Bs[128 * 32];
    __shared__ u16 vt_tile[MODE == 0 ? 128 * 136 : 1];
    int t = threadIdx.x;
    int lane = t & 63, w = t >> 6;
    int wm = w & 1, wn = w >> 1;
    int ln = lane & 15, quad = lane >> 4;
    int m0 = blockIdx.x * 128, n0 = blockIdx.y * 128;
    const u16* Ab = A + m0 * K;
    const u16* Bb = Bt + n0 * K;
    f32x4 acc[4][4] = {};
    int nk = K >> 5;
    for (int kt = 0; kt < nk; ++kt) {
        int k0 = kt * 32;
#pragma unroll
        for (int rr = 0; rr < 2; ++rr) {
            int idx = rr * 256 + t;
            int row = idx >> 2, c = (idx & 3) ^ (row & 3);
            gl_lds16(Ab + row * K + k0 + c * 8, ((char*)As) + idx * 16);
            gl_lds16(Bb + row * K + k0 + c * 8, ((char*)Bs) + idx * 16);
        }
        __syncthreads();
        bf16x8 af[4], bfr[4];
#pragma unroll
        for (int mb = 0; mb < 4; ++mb) {
            int row = wm * 64 + mb * 16 + ln;
            af[mb] = *(const bf16x8*)&As[row * 32 + ((quad ^ (row & 3)) << 3)];
        }
#pragma unroll
        for (int nb = 0; nb < 4; ++nb) {
            int row = wn * 64 + nb * 16 + ln;
            bfr[nb] = *(const bf16x8*)&Bs[row * 32 + ((quad ^ (row & 3)) << 3)];
        }
#pragma unroll
        for (int mb = 0; mb < 4; ++mb)
#pragma unroll
            for (int nb = 0; nb < 4; ++nb)
                acc[mb][nb] = MFMA16(af[mb], bfr[nb], acc[mb][nb]);
        __syncthreads();
    }
    // epilogue — C/D layout: col = lane&15, row = quad*4 + reg
    if (MODE == 0 && n0 >= 2048) {
        // v-region: transpose via LDS, store Vt[bh][d][s] coalesced
#pragma unroll
        for (int mb = 0; mb < 4; ++mb)
#pragma unroll
            for (int nb = 0; nb < 4; ++nb)
#pragma unroll
                for (int r = 0; r < 4; ++r) {
                    int np = wn * 64 + nb * 16 + ln;          // n - n0
                    int mp = wm * 64 + mb * 16 + quad * 4 + r; // m - m0 (= s offset)
                    vt_tile[np * 136 + mp] = f2b(acc[mb][nb][r]);
                }
        __syncthreads();
        int h0 = (n0 >> 6) & 15;
        int b = m0 >> 11;
        int s0 = m0 & 2047;                // s-base within the batch
#pragma unroll
        for (int j = 0; j < 8; ++j) {
            int e = j * 256 + t;
            int d_all = e >> 4;            // n' in [0,128): h_off*64 + d
            int sc = e & 15;
            int hh = h0 + (d_all >> 6);
            int d = d_all & 63;
            u16x8 val = *(const u16x8*)&vt_tile[d_all * 136 + sc * 8];
            *(u16x8*)(v_out + (b * 16 + hh) * 131072 + d * 2048 + s0 + sc * 8) = val;
        }
    } else {
#pragma unroll
        for (int mb = 0; mb < 4; ++mb)
#pragma unroll
            for (int nb = 0; nb < 4; ++nb)
#pragma unroll
                for (int r = 0; r < 4; ++r) {
                    int m = m0 + wm * 64 + mb * 16 + quad * 4 + r;
                    int n = n0 + wn * 64 + nb * 16 + ln;
                    float v = acc[mb][nb][r];
                    if (MODE == 0) {
                        int which = n >> 10, h = (n >> 6) & 15, d = n & 63;
                        int b = m >> 11, s = m & 2047;
                        u16* dst = (which == 0) ? q_out : k_out;
                        float scale = (which == 0) ? LOG2E : 1.0f;
                        dst[(((b << 4) + h) * 2048 + s) * 64 + d] = f2b(v * scale);
                    } else {
                        f_out[m * N + n] = v;
                    }
                }
    }
}

// ---------------- Flash attention: 128-q block = two sequential replicas of the
// proven 64-q pass over one staged K/V tile. Pass A: q0=Q0, pass B: q0=Q0+64.
// sb[j] = tab[h][1921 - Q0 + j] covers exactly the needed window [1921-Q0, 4095-Q0].
__global__ __launch_bounds__(256, 3) void attn_kernel(
        const u16* __restrict__ Qb, const u16* __restrict__ Kb,
        const u16* __restrict__ Vt, const float* __restrict__ bias_tab,
        u16* __restrict__ ctx) {
    __shared__ u16 Ks[128 * 64];     // [key][d], swizzled (chunk ^ (key&7))
    __shared__ u16 Vs[64 * 128];     // [d][key], swizzled (chunk ^ (d&7))
    __shared__ u16 Ps[4][16 * 64];   // per-wave [q16][key64], swizzled
    __shared__ float sb[2176];       // bias slice (already *log2e)
    int t = threadIdx.x;
    int lane = t & 63, w = t >> 6;
    int ln = lane & 15, quad = lane >> 4;
    int bh = blockIdx.x >> 4;        // grid 1024: bh in [0,64)
    int qt = blockIdx.x & 15;
    int h = bh & 15, b = bh >> 4;
    int Q0 = qt * 128;

    float chi = bias_tab[h * 4096 + 2048 + 1500];   // delta >= 128 bucket
    float clo = bias_tab[h * 4096 + 2048 - 1500];   // delta <= -128 bucket

    // sb[j] = tab[h][1921 - Q0 + j]
    const float* tb = bias_tab + h * 4096 + (1921 - Q0);
    for (int i = t; i < 2175; i += 256) sb[i] = tb[i];

    // Q fragments (B-operand: n = lane&15, k = quad*8+j), scalar vars per pass
    const u16* qpA = Qb + (bh * 2048 + Q0 + w * 16 + ln) * 64 + quad * 8;
    bf16x8 qfA0 = *(const bf16x8*)(qpA);
    bf16x8 qfA1 = *(const bf16x8*)(qpA + 32);
    const u16* qpB = qpA + 4096;     // +64 q-rows
    bf16x8 qfB0 = *(const bf16x8*)(qpB);
    bf16x8 qfB1 = *(const bf16x8*)(qpB + 32);

    const u16* Kbase = Kb + bh * 2048 * 64;
    const u16* Vbase = Vt + bh * 64 * 2048;

    f32x4 oaccA[4] = {};
    f32x4 oaccB[4] = {};
    float lA = 0.0f, lB = 0.0f;
    int cb_base = 63 - w * 16 + quad * 4 - ln;
    int swl = ln & 7;

    for (int kt = 0; kt < 16; ++kt) {
        int kb0 = kt * 128;
        // ---- stage K tile (16KB) and V tile (16KB), swizzled ----
#pragma unroll
        for (int it = 0; it < 4; ++it) {
            int idx = it * 256 + t;
            int row = idx >> 3, c = (idx & 7) ^ (row & 7);
            gl_lds16(Kbase + (kb0 + row) * 64 + c * 8, ((char*)Ks) + idx * 16);
        }
#pragma unroll
        for (int it = 0; it < 4; ++it) {
            int idx = it * 256 + t;
            int row = idx >> 4, c = (idx & 15) ^ (row & 7);
            gl_lds16(Vbase + row * 2048 + kb0 + c * 8, ((char*)Vs) + idx * 16);
        }
        __syncthreads();

        // ================= PASS A (q0 = Q0) =================
        {
            f32x4 sacc[8];
            int diff = kb0 - Q0;
            if (diff >= 192 || diff <= -256) {
                float c0 = (diff > 0) ? chi : clo;
                f32x4 ci = {c0, c0, c0, c0};
#pragma unroll
                for (int nb = 0; nb < 8; ++nb) {
                    int key = nb * 16 + ln;
                    int sw = key & 7;
                    bf16x8 kf0 = *(const bf16x8*)&Ks[key * 64 + ((quad ^ sw) << 3)];
                    bf16x8 kf1 = *(const bf16x8*)&Ks[key * 64 + (((quad ^ 4) ^ sw) << 3)];
                    f32x4 scc = MFMA16(kf0, qfA0, ci);
                    sacc[nb] = MFMA16(kf1, qfA1, scc);
                }
            } else {
                int cb = kb0 + cb_base + 64;   // sb-window offset for pass A
#pragma unroll
                for (int nb = 0; nb < 8; ++nb) {
                    int key = nb * 16 + ln;
                    int sw = key & 7;
                    const float* bp = &sb[cb + nb * 16];
                    f32x4 ci = {bp[0], bp[1], bp[2], bp[3]};
                    bf16x8 kf0 = *(const bf16x8*)&Ks[key * 64 + ((quad ^ sw) << 3)];
                    bf16x8 kf1 = *(const bf16x8*)&Ks[key * 64 + (((quad ^ 4) ^ sw) << 3)];
                    f32x4 scc = MFMA16(kf0, qfA0, ci);
                    sacc[nb] = MFMA16(kf1, qfA1, scc);
                }
            }
            float p[8][4];
            float ls0 = 0.f, ls1 = 0.f, ls2 = 0.f, ls3 = 0.f;
#pragma unroll
            for (int nb = 0; nb < 8; ++nb) {
                float e0 = __builtin_amdgcn_exp2f(sacc[nb][0]);
                float e1 = __builtin_amdgcn_exp2f(sacc[nb][1]);
                float e2 = __builtin_amdgcn_exp2f(sacc[nb][2]);
                float e3 = __builtin_amdgcn_exp2f(sacc[nb][3]);
                p[nb][0] = e0; p[nb][1] = e1; p[nb][2] = e2; p[nb][3] = e3;
                ls0 += e0; ls1 += e1; ls2 += e2; ls3 += e3;
            }
            lA += (ls0 + ls1) + (ls2 + ls3);
            u16* pw = &Ps[w][0];
#pragma unroll
            for (int half = 0; half < 2; ++half) {
#pragma unroll
                for (int nbh = 0; nbh < 4; ++nbh) {
                    int nb = half * 4 + nbh;
                    u32 a0 = __builtin_bit_cast(u32, p[nb][0]) + 0x8000u;
                    u32 a1 = __builtin_bit_cast(u32, p[nb][1]) + 0x8000u;
                    u32 a2 = __builtin_bit_cast(u32, p[nb][2]) + 0x8000u;
                    u32 a3 = __builtin_bit_cast(u32, p[nb][3]) + 0x8000u;
                    u32 lo = __builtin_amdgcn_perm(a1, a0, 0x07060302);
                    u32 hi = __builtin_amdgcn_perm(a3, a2, 0x07060302);
                    int c = nbh * 2 + (quad >> 1);
                    u32* dst = (u32*)&pw[ln * 64 + ((c ^ swl) << 3) + (quad & 1) * 4];
                    dst[0] = lo;
                    dst[1] = hi;
                }
#pragma unroll
                for (int kc = 0; kc < 2; ++kc) {
                    bf16x8 pf = *(const bf16x8*)&pw[ln * 64 + (((kc * 4 + quad) ^ swl) << 3)];
#pragma unroll
                    for (int nb = 0; nb < 4; ++nb) {
                        int d = nb * 16 + ln;
                        int vc = (half * 8 + kc * 4 + quad) ^ (d & 7);
                        bf16x8 vf = *(const bf16x8*)&Vs[d * 128 + (vc << 3)];
                        oaccA[nb] = MFMA16(pf, vf, oaccA[nb]);
                    }
                }
            }
        }

        // ================= PASS B (q0 = Q0 + 64) =================
        {
            f32x4 sacc[8];
            int diff = kb0 - Q0 - 64;
            if (diff >= 192 || diff <= -256) {
                float c0 = (diff > 0) ? chi : clo;
                f32x4 ci = {c0, c0, c0, c0};
#pragma unroll
                for (int nb = 0; nb < 8; ++nb) {
                    int key = nb * 16 + ln;
                    int sw = key & 7;
                    bf16x8 kf0 = *(const bf16x8*)&Ks[key * 64 + ((quad ^ sw) << 3)];
                    bf16x8 kf1 = *(const bf16x8*)&Ks[key * 64 + (((quad ^ 4) ^ sw) << 3)];
                    f32x4 scc = MFMA16(kf0, qfB0, ci);
                    sacc[nb] = MFMA16(kf1, qfB1, scc);
                }
            } else {
                int cb = kb0 + cb_base;        // sb-window offset for pass B
#pragma unroll
                for (int nb = 0; nb < 8; ++nb) {
                    int key = nb * 16 + ln;
                    int sw = key & 7;
                    const float* bp = &sb[cb + nb * 16];
                    f32x4 ci = {bp[0], bp[1], bp[2], bp[3]};
                    bf16x8 kf0 = *(const bf16x8*)&Ks[key * 64 + ((quad ^ sw) << 3)];
                    bf16x8 kf1 = *(const bf16x8*)&Ks[key * 64 + (((quad ^ 4) ^ sw) << 3)];
                    f32x4 scc = MFMA16(kf0, qfB0, ci);
                    sacc[nb] = MFMA16(kf1, qfB1, scc);
                }
            }
            float p[8][4];
            float ls0 = 0.f, ls1 = 0.f, ls2 = 0.f, ls3 = 0.f;
#pragma unroll
            for (int nb = 0; nb < 8; ++nb) {
                float e0 = __builtin_amdgcn_exp2f(sacc[nb][0]);
                float e1 = __builtin_amdgcn_exp2f(sacc[nb][1]);
                float e2 = __builtin_amdgcn_exp2f(sacc[nb][2]);
                float e3 = __builtin_amdgcn_exp2f(sacc[nb][3]);
                p[nb][0] = e0; p[nb][1] = e1; p[nb][2] = e2; p[nb][3] = e3;
                ls0 += e0; ls1 += e1; ls2 += e2; ls3 += e3;
            }
            lB += (ls0 + ls1) + (ls2 + ls3);
            u16* pw = &Ps[w][0];
#pragma unroll
            for (int half = 0; half < 2; ++half) {
#pragma unroll
                for (int nbh = 0; nbh < 4; ++nbh) {
                    int nb = half * 4 + nbh;
                    u32 a0 = __builtin_bit_cast(u32, p[nb][0]) + 0x8000u;
                    u32 a1 = __builtin_bit_cast(u32, p[nb][1]) + 0x8000u;
                    u32 a2 = __builtin_bit_cast(u32, p[nb][2]) + 0x8000u;
                    u32 a3 = __builtin_bit_cast(u32, p[nb][3]) + 0x8000u;
                    u32 lo = __builtin_amdgcn_perm(a1, a0, 0x07060302);
                    u32 hi = __builtin_amdgcn_perm(a3, a2, 0x07060302);
                    int c = nbh * 2 + (quad >> 1);
                    u32* dst = (u32*)&pw[ln * 64 + ((c ^ swl) << 3) + (quad & 1) * 4];
                    dst[0] = lo;
                    dst[1] = hi;
                }
#pragma unroll
                for (int kc = 0; kc < 2; ++kc) {
                    bf16x8 pf = *(const bf16x8*)&pw[ln * 64 + (((kc * 4 + quad) ^ swl) << 3)];
#pragma unroll
                    for (int nb = 0; nb < 4; ++nb) {
                        int d = nb * 16 + ln;
                        int vc = (half * 8 + kc * 4 + quad) ^ (d & 7);
                        bf16x8 vf = *(const bf16x8*)&Vs[d * 128 + (vc << 3)];
                        oaccB[nb] = MFMA16(pf, vf, oaccB[nb]);
                    }
                }
            }
        }
        __syncthreads();
    }

    // ---- epilogue ----
    {
        float l = lA;
        l += __shfl_xor(l, 16);
        l += __shfl_xor(l, 32);
        float linv = 1.0f / l;
#pragma unroll
        for (int r = 0; r < 4; ++r) {
            float lr = __shfl(linv, quad * 4 + r);
            int q = Q0 + w * 16 + quad * 4 + r;
#pragma unroll
            for (int nb = 0; nb < 4; ++nb)
                ctx[(b * 2048 + q) * 1024 + h * 64 + nb * 16 + ln] = f2b(oaccA[nb][r] * lr);
        }
    }
    {
        float l = lB;
        l += __shfl_xor(l, 16);
        l += __shfl_xor(l, 32);
        float linv = 1.0f / l;
#pragma unroll
        for (int r = 0; r < 4; ++r) {
            float lr = __shfl(linv, quad * 4 + r);
            int q = Q0 + 64 + w * 16 + quad * 4 + r;
#pragma unroll
            for (int nb = 0; nb < 4; ++nb)
                ctx[(b * 2048 + q) * 1024 + h * 64 + nb * 16 + ln] = f2b(oaccB[nb][r] * lr);
        }
    }
}

// ---------------- launch ----------------
extern "C" void kernel_launch(void* const* d_in, const int* in_sizes, int n_in,
                              void* d_out, int out_size, void* d_ws, size_t ws_size,
                              hipStream_t stream) {
    const float* H   = (const float*)d_in[0];
    const float* wq  = (const float*)d_in[1];
    const float* wk  = (const float*)d_in[2];
    const float* wv  = (const float*)d_in[3];
    const float* wo  = (const float*)d_in[4];
    const float* rel = (const float*)d_in[5];
    float* out = (float*)d_out;

    char* ws = (char*)d_ws;
    u16* Hb    = (u16*)(ws);                 // 16.78 MB; reused as ctx after gemm<0>
    u16* Wt    = (u16*)(ws + 16777216);      // 6.29 MB (wq|wk|wv transposed)
    u16* Wot   = (u16*)(ws + 23068672);      // 2.10 MB
    u16* Qb    = (u16*)(ws + 25165824);      // 16.78 MB
    u16* Kb    = (u16*)(ws + 41943040);      // 16.78 MB
    u16* Vt    = (u16*)(ws + 58720256);      // 16.78 MB, [bh][d][s]
    float* bias_tab = (float*)(ws + 75497472); // 0.26 MB
    u16* ctx = Hb;

    prep_kernel<<<5376, 256, 0, stream>>>(H, wq, wk, wv, wo, rel, Hb, Wt, Wot, bias_tab);
    gemm_bt<0><<<dim3(64, 24), 256, 0, stream>>>(Hb, Wt, 1024, 3072, Qb, Kb, Vt, nullptr);
    attn_kernel<<<1024, 256, 0, stream>>>(Qb, Kb, Vt, bias_tab, ctx);
    gemm_bt<1><<<dim3(64, 8), 256, 0, stream>>>(ctx, Wot, 1024, 1024, nullptr, nullptr, nullptr, out);
}